// Round 12
// baseline (470.465 us; speedup 1.0000x reference)
//
#include <hip/hip_runtime.h>
#include <cstdint>
#include <cstddef>

// Problem constants: V=32000 D=1024 T=1024 H=16 HD=64 B=4
// ws layout (bytes):
//   xb     @ 0          8,388,608   x bf16 [4096][1024]  (reused as h2)
//   wqkvT  @ 8388608    6,291,456   [3072][1024] bf16
//   w1T    @ 14680064   2,097,152
//   w2T    @ 16777216   2,097,152
//   woutT  @ 18874368   65,536,000  [32000][1024] bf16
//   qbuf   @ 84410368   8,388,608   [B,H,T,64] bf16
//   kbuf   @ 92798976   8,388,608
//   vbuf   @ 101187584  8,388,608
//   attx   @ 109576192  8,388,608
//   h1     @ 117964800  8,388,608

#define DEV __device__ __forceinline__

typedef __attribute__((ext_vector_type(8))) short bf16x8;
typedef __attribute__((ext_vector_type(4))) float f32x4;

DEV unsigned short f2bf(float f) {
  unsigned u = __float_as_uint(f);
  u = (u + 0x7fffu + ((u >> 16) & 1u)) >> 16;
  return (unsigned short)u;
}

DEV void stage16(const void* g, void* l) {   // async global->LDS, 16B/lane
  __builtin_amdgcn_global_load_lds(
      (const __attribute__((address_space(1))) unsigned int*)g,
      (__attribute__((address_space(3))) unsigned int*)l, 16, 0, 0);
}

// ---------------- prep: embed (blocks 0..4095) + pack_qkv (4096..4863) ------
__global__ __launch_bounds__(256) void k_prep(
    const int* __restrict__ idx, const float* __restrict__ tok,
    const float* __restrict__ pos, unsigned short* __restrict__ xb,
    const float* __restrict__ Wq, const float* __restrict__ Wk,
    const float* __restrict__ Wv, unsigned short* __restrict__ wqkvT) {
  __shared__ float tile[64][65];
  int b = blockIdx.x;
  int tid = threadIdx.x;
  if (b < 4096) {
    int i = b * 256 + tid;
    int row = i >> 8;
    int c4 = i & 255;
    int t = row & 1023;
    int tokid = idx[row];
    const float4 a = ((const float4*)tok)[(size_t)tokid * 256 + c4];
    const float4 p = ((const float4*)pos)[(size_t)t * 256 + c4];
    ushort4 o;
    o.x = f2bf(a.x + p.x); o.y = f2bf(a.y + p.y);
    o.z = f2bf(a.z + p.z); o.w = f2bf(a.w + p.w);
    ((ushort4*)xb)[i] = o;
    return;
  }
  int blk = b - 4096;
  int p = blk >> 8, h = (blk >> 4) & 15, d0 = (blk & 15) * 64;
  const float* W = (p == 0) ? Wq : ((p == 1) ? Wk : Wv);
  int rq = tid >> 6, cc = tid & 63;
#pragma unroll
  for (int it = 0; it < 16; ++it) {
    int dr = it * 4 + rq;
    tile[dr][cc] = W[((size_t)h * 1024 + d0 + dr) * 64 + cc];
  }
  __syncthreads();
#pragma unroll
  for (int it = 0; it < 16; ++it) {
    int e = it * 4 + rq;
    wqkvT[((size_t)(p * 1024 + h * 64 + e)) * 1024 + d0 + cc] = f2bf(tile[cc][e]);
  }
}

// ------- fused launch: QKV GEMM (blocks 0..767) + weight transposes --------
// GEMM blocks are compute-leaning; transpose blocks (memory-bound) backfill
// the CU slots and idle memory pipe -> overlap (saves ~serial transpose time).
__global__ __launch_bounds__(256, 2) void k_qkv_tr(
    const unsigned short* __restrict__ A, const unsigned short* __restrict__ Bt,
    unsigned short* __restrict__ qbuf, unsigned short* __restrict__ kbuf,
    unsigned short* __restrict__ vbuf,
    const float* __restrict__ W1, const float* __restrict__ W2,
    const float* __restrict__ Wout, unsigned short* __restrict__ w1T,
    unsigned short* __restrict__ w2T, unsigned short* __restrict__ woutT) {
  __shared__ __align__(16) unsigned char sraw[65536];   // union: gemm 64KB / tr 16.6KB
  const int tid = threadIdx.x;
  int b = blockIdx.x;

  if (b >= 768) {
    // ---- transpose part: 8512 blocks ----
    b -= 768;
    const float* in;
    unsigned short* outp;
    int C, bx, by;
    if (b < 256)      { in = W1;   outp = w1T;   C = 1024;  bx = b & 15; by = b >> 4; }
    else if (b < 512) { b -= 256; in = W2;  outp = w2T;  C = 1024;  bx = b & 15; by = b >> 4; }
    else              { b -= 512; in = Wout; outp = woutT; C = 32000; bx = b % 500; by = b / 500; }
    const int R = 1024;
    const int c0 = bx * 64, r0 = by * 64;
    float* tile = (float*)sraw;                 // [64][65]
    int rq = tid >> 6, cc = tid & 63;
#pragma unroll
    for (int it = 0; it < 16; ++it) {
      int r = it * 4 + rq;
      tile[r * 65 + cc] = in[(size_t)(r0 + r) * C + c0 + cc];
    }
    __syncthreads();
#pragma unroll
    for (int it = 0; it < 16; ++it) {
      int c = it * 4 + rq;
      outp[(size_t)(c0 + c) * R + r0 + cc] = f2bf(tile[cc * 65 + c]);
    }
    return;
  }

  // ---- GEMM part: identical to r11 k_gemm128p<3> with grid (24,32) ----
  const int M = 4096, N = 3072, K = 1024;
  unsigned short* sm = (unsigned short*)sraw;
  const int lane = tid & 63, w = tid >> 6;
  const int wr = w >> 1, wc = w & 1;
  const int fr = lane & 15, fg = lane >> 4;
  const int pch = (fg ^ ((fr >> 1) & 3)) << 3;

  const int nwg = 768;
  int wg = b;
  wg = (wg & 7) * (nwg >> 3) + (wg >> 3);      // XCD swizzle (768 % 8 == 0)
  const int m0 = (wg % 32) * 128;
  const int n0 = (wg / 32) * 128;

  const int srow = tid >> 2;
  const int sch = (((tid & 3) ^ ((srow >> 1) & 3))) * 8;
  const unsigned short* Ab0 = A + (size_t)(m0 + srow) * K + sch;
  const unsigned short* Ab1 = A + (size_t)(m0 + 64 + srow) * K + sch;
  const unsigned short* Bb0 = Bt + (size_t)(n0 + srow) * K + sch;
  const unsigned short* Bb1 = Bt + (size_t)(n0 + 64 + srow) * K + sch;
  const int NT = K >> 5;

#define STAGE_T(t, bb)                                                      \
  do {                                                                      \
    stage16(Ab0 + (t) * 32, &sm[(bb) * 8192 + tid * 8]);                    \
    stage16(Ab1 + (t) * 32, &sm[(bb) * 8192 + 2048 + tid * 8]);             \
    stage16(Bb0 + (t) * 32, &sm[(bb) * 8192 + 4096 + tid * 8]);             \
    stage16(Bb1 + (t) * 32, &sm[(bb) * 8192 + 6144 + tid * 8]);             \
  } while (0)

#define RD_ALL(dA, dB, bb)                                                  \
  do {                                                                      \
    const unsigned short* b_ = &sm[(bb) * 8192];                            \
    _Pragma("unroll") for (int m_ = 0; m_ < 4; ++m_)                        \
      dA[m_] = *(const bf16x8*)&b_[(wr * 64 + m_ * 16 + fr) * 32 + pch];    \
    _Pragma("unroll") for (int n_ = 0; n_ < 4; ++n_)                        \
      dB[n_] = *(const bf16x8*)&b_[4096 + (wc * 64 + n_ * 16 + fr) * 32 + pch]; \
  } while (0)

#define MFMA16(a, b)                                                        \
  do {                                                                      \
    __builtin_amdgcn_s_setprio(1);                                          \
    _Pragma("unroll") for (int m_ = 0; m_ < 4; ++m_)                        \
    _Pragma("unroll") for (int n_ = 0; n_ < 4; ++n_)                        \
      acc[m_][n_] = __builtin_amdgcn_mfma_f32_16x16x32_bf16(                \
          a[m_], b[n_], acc[m_][n_], 0, 0, 0);                              \
    __builtin_amdgcn_s_setprio(0);                                          \
  } while (0)

#define TB128(t, cA, cB, nA, nB)                                            \
  do {                                                                      \
    if ((t) + 3 < NT) STAGE_T((t) + 3, ((t) + 3) & 3);                      \
    if ((t) + 1 < NT) RD_ALL(nA, nB, ((t) + 1) & 3);                        \
    MFMA16(cA, cB);                                                         \
    if ((t) + 3 < NT) {                                                     \
      asm volatile("s_waitcnt vmcnt(4)" ::: "memory");                      \
    } else {                                                                \
      asm volatile("s_waitcnt vmcnt(0)" ::: "memory");                      \
    }                                                                       \
    __builtin_amdgcn_s_barrier();                                           \
  } while (0)

  f32x4 zero = {0.f, 0.f, 0.f, 0.f};
  f32x4 acc[4][4];
#pragma unroll
  for (int m = 0; m < 4; ++m)
#pragma unroll
    for (int n = 0; n < 4; ++n) acc[m][n] = zero;

  STAGE_T(0, 0); STAGE_T(1, 1); STAGE_T(2, 2);
  asm volatile("s_waitcnt vmcnt(4)" ::: "memory");
  __builtin_amdgcn_s_barrier();

  bf16x8 xA[4], xB[4], yA[4], yB[4];
  RD_ALL(xA, xB, 0);
  for (int t = 0; t < NT; t += 2) {
    TB128(t, xA, xB, yA, yB);
    TB128(t + 1, yA, yB, xA, xB);
  }
#undef STAGE_T
#undef RD_ALL
#undef MFMA16
#undef TB128

#pragma unroll
  for (int m = 0; m < 4; ++m) {
#pragma unroll
    for (int n = 0; n < 4; ++n) {
      const int rb = m0 + wr * 64 + m * 16 + fg * 4;
      const int cc = n0 + wc * 64 + n * 16 + fr;
#pragma unroll
      for (int i = 0; i < 4; ++i) {
        float v = acc[m][n][i];
        const int r = rb + i;
        int p = cc >> 10, rem = cc & 1023;
        int h = rem >> 6, e = rem & 63;
        int bb2 = r >> 10, t2 = r & 1023;
        unsigned short* dst = (p == 0) ? qbuf : ((p == 1) ? kbuf : vbuf);
        dst[(((size_t)(bb2 * 16 + h) * 1024) + t2) * 64 + e] = f2bf(v);
      }
    }
  }
}

// ------- pipelined 128x128 GEMM (FFN): r9 structure, 2 blocks/CU ------------
__global__ __launch_bounds__(256, 2) void k_gemm128p(
    const unsigned short* __restrict__ A, const unsigned short* __restrict__ Bt,
    const float* __restrict__ bias, unsigned short* __restrict__ out0,
    int M, int N, int K) {
  __shared__ __align__(16) unsigned short sm[4 * 8192];  // shorts; 64 KB
  const int tid = threadIdx.x;
  const int lane = tid & 63, w = tid >> 6;
  const int wr = w >> 1, wc = w & 1;
  const int fr = lane & 15, fg = lane >> 4;
  const int pch = (fg ^ ((fr >> 1) & 3)) << 3;

  const int nwg = gridDim.x * gridDim.y;
  int wg = blockIdx.y * gridDim.x + blockIdx.x;
  if ((nwg & 7) == 0) wg = (wg & 7) * (nwg >> 3) + (wg >> 3);
  const int m0 = (wg % gridDim.y) * 128;
  const int n0 = (wg / gridDim.y) * 128;

  const int srow = tid >> 2;
  const int sch = (((tid & 3) ^ ((srow >> 1) & 3))) * 8;
  const unsigned short* Ab0 = A + (size_t)(m0 + srow) * K + sch;
  const unsigned short* Ab1 = A + (size_t)(m0 + 64 + srow) * K + sch;
  const unsigned short* Bb0 = Bt + (size_t)(n0 + srow) * K + sch;
  const unsigned short* Bb1 = Bt + (size_t)(n0 + 64 + srow) * K + sch;
  const int NT = K >> 5;

#define STAGE_T(t, bb)                                                      \
  do {                                                                      \
    stage16(Ab0 + (t) * 32, &sm[(bb) * 8192 + tid * 8]);                    \
    stage16(Ab1 + (t) * 32, &sm[(bb) * 8192 + 2048 + tid * 8]);             \
    stage16(Bb0 + (t) * 32, &sm[(bb) * 8192 + 4096 + tid * 8]);             \
    stage16(Bb1 + (t) * 32, &sm[(bb) * 8192 + 6144 + tid * 8]);             \
  } while (0)

#define RD_ALL(dA, dB, bb)                                                  \
  do {                                                                      \
    const unsigned short* b_ = &sm[(bb) * 8192];                            \
    _Pragma("unroll") for (int m_ = 0; m_ < 4; ++m_)                        \
      dA[m_] = *(const bf16x8*)&b_[(wr * 64 + m_ * 16 + fr) * 32 + pch];    \
    _Pragma("unroll") for (int n_ = 0; n_ < 4; ++n_)                        \
      dB[n_] = *(const bf16x8*)&b_[4096 + (wc * 64 + n_ * 16 + fr) * 32 + pch]; \
  } while (0)

#define MFMA16(a, b)                                                        \
  do {                                                                      \
    __builtin_amdgcn_s_setprio(1);                                          \
    _Pragma("unroll") for (int m_ = 0; m_ < 4; ++m_)                        \
    _Pragma("unroll") for (int n_ = 0; n_ < 4; ++n_)                        \
      acc[m_][n_] = __builtin_amdgcn_mfma_f32_16x16x32_bf16(                \
          a[m_], b[n_], acc[m_][n_], 0, 0, 0);                              \
    __builtin_amdgcn_s_setprio(0);                                          \
  } while (0)

#define TB128(t, cA, cB, nA, nB)                                            \
  do {                                                                      \
    if ((t) + 3 < NT) STAGE_T((t) + 3, ((t) + 3) & 3);                      \
    if ((t) + 1 < NT) RD_ALL(nA, nB, ((t) + 1) & 3);                        \
    MFMA16(cA, cB);                                                         \
    if ((t) + 3 < NT) {                                                     \
      asm volatile("s_waitcnt vmcnt(4)" ::: "memory");                      \
    } else {                                                                \
      asm volatile("s_waitcnt vmcnt(0)" ::: "memory");                      \
    }                                                                       \
    __builtin_amdgcn_s_barrier();                                           \
  } while (0)

  f32x4 zero = {0.f, 0.f, 0.f, 0.f};
  f32x4 acc[4][4];
#pragma unroll
  for (int m = 0; m < 4; ++m)
#pragma unroll
    for (int n = 0; n < 4; ++n) acc[m][n] = zero;

  STAGE_T(0, 0); STAGE_T(1, 1); STAGE_T(2, 2);
  asm volatile("s_waitcnt vmcnt(4)" ::: "memory");
  __builtin_amdgcn_s_barrier();

  bf16x8 xA[4], xB[4], yA[4], yB[4];
  RD_ALL(xA, xB, 0);
  for (int t = 0; t < NT; t += 2) {
    TB128(t, xA, xB, yA, yB);
    TB128(t + 1, yA, yB, xA, xB);
  }
#undef STAGE_T
#undef RD_ALL
#undef MFMA16
#undef TB128

#pragma unroll
  for (int m = 0; m < 4; ++m) {
#pragma unroll
    for (int n = 0; n < 4; ++n) {
      const int rb = m0 + wr * 64 + m * 16 + fg * 4;
      const int cc = n0 + wc * 64 + n * 16 + fr;
#pragma unroll
      for (int i = 0; i < 4; ++i) {
        float v = acc[m][n][i] + bias[cc];
        v = v > 0.f ? v : 0.f;
        out0[(size_t)(rb + i) * N + cc] = f2bf(v);
      }
    }
  }
}

// ---------- 256x256 logits GEMM: r9 loop + LDS-coalesced NT epilogue --------
__global__ __launch_bounds__(512, 2) void k_gemm256(
    const unsigned short* __restrict__ A, const unsigned short* __restrict__ Bt,
    const float* __restrict__ bias, float* __restrict__ out,
    int M, int N, int K) {
  __shared__ __align__(16) unsigned short sm[4 * 16384];   // 128 KB
  const int tid = threadIdx.x;
  const int lane = tid & 63, wid = tid >> 6;
  const int wr = wid >> 2, wc = wid & 3;          // 2 x 4 wave grid
  const int fr = lane & 15, fg = lane >> 4;
  const int pch = (fg ^ ((fr >> 1) & 3)) << 3;    // swizzled read chunk

  const int nwg = gridDim.x * gridDim.y;
  int wg = blockIdx.y * gridDim.x + blockIdx.x;
  if ((nwg & 7) == 0) wg = (wg & 7) * (nwg >> 3) + (wg >> 3);
  const int m0 = (wg % gridDim.y) * 256;
  const int n0 = (wg / gridDim.y) * 256;

  const int srow = tid >> 2;
  const int scol = (((tid & 3) ^ ((srow >> 1) & 3))) * 8;  // pre-swizzled
  const int NT = K >> 5;                                   // 32 K-tiles of 32

#define STAGE_A(t, bb)                                                      \
  do {                                                                      \
    const unsigned short* g = A + (size_t)(m0 + srow) * K + (t) * 32 + scol; \
    stage16(g, &sm[(bb) * 16384 + tid * 8]);                                \
    stage16(g + (size_t)128 * K, &sm[(bb) * 16384 + 4096 + tid * 8]);       \
  } while (0)
#define STAGE_B(t, bb)                                                      \
  do {                                                                      \
    const unsigned short* g = Bt + (size_t)(n0 + srow) * K + (t) * 32 + scol; \
    stage16(g, &sm[(bb) * 16384 + 8192 + tid * 8]);                         \
    stage16(g + (size_t)128 * K, &sm[(bb) * 16384 + 8192 + 4096 + tid * 8]); \
  } while (0)

#define RD_G0(dA, dB, base)                                                 \
  do {                                                                      \
    _Pragma("unroll") for (int m_ = 0; m_ < 4; ++m_)                        \
      dA[m_] = *(const bf16x8*)&(base)[(wr * 128 + m_ * 16 + fr) * 32 + pch]; \
    _Pragma("unroll") for (int n_ = 0; n_ < 4; ++n_)                        \
      dB[n_] = *(const bf16x8*)&(base)[8192 + (wc * 64 + n_ * 16 + fr) * 32 + pch]; \
  } while (0)
#define RD_AHI(dA, base)                                                    \
  do {                                                                      \
    _Pragma("unroll") for (int m_ = 0; m_ < 4; ++m_)                        \
      dA[m_] = *(const bf16x8*)&(base)[(wr * 128 + (m_ + 4) * 16 + fr) * 32 + pch]; \
  } while (0)

#define MFMA_G(rbase, a, b)                                                 \
  do {                                                                      \
    __builtin_amdgcn_s_setprio(1);                                          \
    _Pragma("unroll") for (int m_ = 0; m_ < 4; ++m_)                        \
    _Pragma("unroll") for (int n_ = 0; n_ < 4; ++n_)                        \
      acc[(rbase) + m_][n_] = __builtin_amdgcn_mfma_f32_16x16x32_bf16(      \
          a[m_], b[n_], acc[(rbase) + m_][n_], 0, 0, 0);                    \
    __builtin_amdgcn_s_setprio(0);                                          \
  } while (0)

#define TILE_BODY(t, curA, curB, nxtA, nxtB)                                \
  do {                                                                      \
    const unsigned short* Ab_ = &sm[((t) & 3) * 16384];                     \
    bf16x8 a1_[4];                                                          \
    RD_AHI(a1_, Ab_);                                                       \
    if ((t) + 3 < NT) STAGE_A((t) + 3, ((t) + 3) & 3);                      \
    MFMA_G(0, curA, curB);                                                  \
    if ((t) + 1 < NT) {                                                     \
      const unsigned short* An_ = &sm[(((t) + 1) & 3) * 16384];             \
      RD_G0(nxtA, nxtB, An_);                                               \
    }                                                                       \
    if ((t) + 3 < NT) STAGE_B((t) + 3, ((t) + 3) & 3);                      \
    MFMA_G(4, a1_, curB);                                                   \
    if ((t) + 3 < NT) {                                                     \
      asm volatile("s_waitcnt vmcnt(4)" ::: "memory");                      \
    } else {                                                                \
      asm volatile("s_waitcnt vmcnt(0)" ::: "memory");                      \
    }                                                                       \
    __builtin_amdgcn_s_barrier();                                           \
  } while (0)

  f32x4 zero = {0.f, 0.f, 0.f, 0.f};
  f32x4 acc[8][4];
#pragma unroll
  for (int m = 0; m < 8; ++m)
#pragma unroll
    for (int n = 0; n < 4; ++n) acc[m][n] = zero;

  STAGE_A(0, 0); STAGE_B(0, 0);
  STAGE_A(1, 1); STAGE_B(1, 1);
  STAGE_A(2, 2); STAGE_B(2, 2);
  asm volatile("s_waitcnt vmcnt(4)" ::: "memory");
  __builtin_amdgcn_s_barrier();

  bf16x8 xA[4], xB[4], yA[4], yB[4];
  RD_G0(xA, xB, &sm[0]);          // tile 0 group-0 regs

  for (int t = 0; t < NT; t += 2) {
    TILE_BODY(t, xA, xB, yA, yB);
    TILE_BODY(t + 1, yA, yB, xA, xB);
  }
#undef STAGE_A
#undef STAGE_B
#undef RD_G0
#undef RD_AHI
#undef MFMA_G
#undef TILE_BODY

  // ---- epilogue: LDS slab transpose -> coalesced f32x4 NT stores ----
  float* lds = (float*)sm;        // [32][260] f32, padded
  float bsv[4];
#pragma unroll
  for (int n = 0; n < 4; ++n) bsv[n] = bias[n0 + wc * 64 + n * 16 + fr];

  for (int m = 0; m < 8; ++m) {
#pragma unroll
    for (int n = 0; n < 4; ++n) {
      const int c = wc * 64 + n * 16 + fr;
#pragma unroll
      for (int i = 0; i < 4; ++i)
        lds[(wr * 16 + fg * 4 + i) * 260 + c] = acc[m][n][i] + bsv[n];
    }
    __syncthreads();
#pragma unroll
    for (int p = 0; p < 4; ++p) {
      const int rr = p * 8 + (tid >> 6);
      const int c4 = (tid & 63) * 4;
      f32x4 v = *(const f32x4*)&lds[rr * 260 + c4];
      const int grow = m0 + ((rr < 16) ? (m * 16 + rr) : (128 + m * 16 + rr - 16));
      __builtin_nontemporal_store(v, (f32x4*)&out[(size_t)grow * N + n0 + c4]);
    }
    __syncthreads();
  }
}

// ---------------- fused causal flash attention, Q-tile 128 ------------------
__global__ __launch_bounds__(256) void k_attn(
    const unsigned short* __restrict__ qb, const unsigned short* __restrict__ kb,
    const unsigned short* __restrict__ vb, unsigned short* __restrict__ attx) {
  __shared__ __align__(16) unsigned short Klds[64][72];
  __shared__ __align__(16) unsigned short Vt[64][72];
  __shared__ __align__(16) unsigned short Plds[2][4][16][72];
  const int wg = blockIdx.x;
  const int xcd = wg & 7, idxr = wg >> 3;
  const int bh = xcd * 8 + (idxr >> 3);     // 8 bh per XCD
  const int qt = 7 - (idxr & 7);            // heavy-first within XCD
  const int tid = threadIdx.x;
  const int w = tid >> 6, lane = tid & 63;
  const int fr = lane & 15, g = lane >> 4;
  const size_t base = (size_t)bh * (1024 * 64);
  const int qbase = qt * 128;

  bf16x8 qf[2][2];
#pragma unroll
  for (int qs = 0; qs < 2; ++qs)
#pragma unroll
    for (int t = 0; t < 2; ++t)
      qf[qs][t] = *(const bf16x8*)&qb[base +
          (size_t)(qbase + qs * 64 + w * 16 + fr) * 64 + t * 32 + g * 8];

  f32x4 zero = {0.f, 0.f, 0.f, 0.f};
  f32x4 o[2][4];
#pragma unroll
  for (int qs = 0; qs < 2; ++qs)
#pragma unroll
    for (int hb = 0; hb < 4; ++hb) o[qs][hb] = zero;
  float m_s[2] = {-3.0e38f, -3.0e38f}, l_s[2] = {0.f, 0.f};

  const int NTKV = 2 * qt + 2;
  for (int jt = 0; jt < NTKV; ++jt) {
    const int kvb = jt * 64;
#pragma unroll
    for (int it = 0; it < 2; ++it) {       // stage K rows + V transposed
      int c = tid + it * 256;
      int r = c >> 3, e0 = (c & 7) * 8;
      uint4 kd = *(const uint4*)&kb[base + (size_t)(kvb + r) * 64 + e0];
      *(uint4*)&Klds[r][e0] = kd;
      uint4 vd = *(const uint4*)&vb[base + (size_t)(kvb + r) * 64 + e0];
      const unsigned short* vs = (const unsigned short*)&vd;
#pragma unroll
      for (int j = 0; j < 8; ++j) Vt[e0 + j][r] = vs[j];
    }
    __syncthreads();

#pragma unroll
    for (int qs = 0; qs < 2; ++qs) {
      const int qlo = qbase + qs * 64;
      if (kvb > qlo + 63) continue;        // fully-masked subtile (uniform)
      const int q_abs = qlo + w * 16 + fr;

      f32x4 st[4];
#pragma unroll
      for (int f = 0; f < 4; ++f) {
        st[f] = zero;
#pragma unroll
        for (int t = 0; t < 2; ++t) {
          bf16x8 kf = *(const bf16x8*)&Klds[f * 16 + fr][t * 32 + g * 8];
          st[f] = __builtin_amdgcn_mfma_f32_16x16x32_bf16(kf, qf[qs][t], st[f],
                                                          0, 0, 0);
        }
      }
      float sv[4][4];
      float tm = -3.0e38f;
#pragma unroll
      for (int f = 0; f < 4; ++f)
#pragma unroll
        for (int i = 0; i < 4; ++i) {
          int kv = kvb + f * 16 + g * 4 + i;
          float s = st[f][i] * 0.125f;
          if (kv > q_abs) s = -3.0e38f;
          sv[f][i] = s;
          tm = fmaxf(tm, s);
        }
      tm = fmaxf(tm, __shfl_xor(tm, 16));
      tm = fmaxf(tm, __shfl_xor(tm, 32));
      float mnew = fmaxf(m_s[qs], tm);
      float scale = expf(m_s[qs] - mnew);
      float lsum = 0.f;
#pragma unroll
      for (int f = 0; f < 4; ++f)
#pragma unroll
        for (int i = 0; i < 4; ++i) {
          float pv = expf(sv[f][i] - mnew);
          lsum += pv;
          Plds[qs][w][fr][f * 16 + g * 4 + i] = f2bf(pv);
        }
      lsum += __shfl_xor(lsum, 16);
      lsum += __shfl_xor(lsum, 32);
      l_s[qs] = l_s[qs] * scale + lsum;
      m_s[qs] = mnew;
#pragma unroll
      for (int i = 0; i < 4; ++i) {
        float sc = __shfl(scale, g * 4 + i);
#pragma unroll
        for (int hb = 0; hb < 4; ++hb) o[qs][hb][i] *= sc;
      }
      asm volatile("s_waitcnt lgkmcnt(0)" ::: "memory");
      __builtin_amdgcn_sched_barrier(0);
#pragma unroll
      for (int t = 0; t < 2; ++t) {
        bf16x8 pf = *(const bf16x8*)&Plds[qs][w][fr][t * 32 + g * 8];
#pragma unroll
        for (int hb = 0; hb < 4; ++hb) {
          bf16x8 vf = *(const bf16x8*)&Vt[hb * 16 + fr][t * 32 + g * 8];
          o[qs][hb] = __builtin_amdgcn_mfma_f32_16x16x32_bf16(pf, vf, o[qs][hb],
                                                              0, 0, 0);
        }
      }
    }
    __syncthreads();                       // all waves done with K/Vt
  }

  const int b = bh >> 4, h = bh & 15;
#pragma unroll
  for (int qs = 0; qs < 2; ++qs) {
    const float inv = 1.f / l_s[qs];
#pragma unroll
    for (int i = 0; i < 4; ++i) {
      float sc = __shfl(inv, g * 4 + i);
      int trow = qbase + qs * 64 + w * 16 + g * 4 + i;
      size_t rowoff = ((size_t)(b * 1024 + trow)) * 1024 + h * 64;
#pragma unroll
      for (int hb = 0; hb < 4; ++hb)
        attx[rowoff + hb * 16 + fr] = f2bf(o[qs][hb][i] * sc);
    }
  }
}

// ------------------------------- launch -------------------------------------
extern "C" void kernel_launch(void* const* d_in, const int* in_sizes, int n_in,
                              void* d_out, int out_size, void* d_ws,
                              size_t ws_size, hipStream_t stream) {
  const int* idx = (const int*)d_in[0];
  const float* tok = (const float*)d_in[1];
  const float* pos = (const float*)d_in[2];
  const float* Wq = (const float*)d_in[3];
  const float* Wk = (const float*)d_in[4];
  const float* Wv = (const float*)d_in[5];
  const float* W1 = (const float*)d_in[6];
  const float* b1 = (const float*)d_in[7];
  const float* W2 = (const float*)d_in[8];
  const float* b2 = (const float*)d_in[9];
  const float* Wout = (const float*)d_in[10];
  const float* bout = (const float*)d_in[11];
  float* out = (float*)d_out;

  char* ws = (char*)d_ws;
  unsigned short* xb    = (unsigned short*)(ws + 0);
  unsigned short* wqkvT = (unsigned short*)(ws + 8388608);
  unsigned short* w1T   = (unsigned short*)(ws + 14680064);
  unsigned short* w2T   = (unsigned short*)(ws + 16777216);
  unsigned short* woutT = (unsigned short*)(ws + 18874368);
  unsigned short* qbuf  = (unsigned short*)(ws + 84410368);
  unsigned short* kbuf  = (unsigned short*)(ws + 92798976);
  unsigned short* vbuf  = (unsigned short*)(ws + 101187584);
  unsigned short* attx  = (unsigned short*)(ws + 109576192);
  unsigned short* h1    = (unsigned short*)(ws + 117964800);
  unsigned short* h2    = xb;

  k_prep<<<4864, 256, 0, stream>>>(idx, tok, pos, xb, Wq, Wk, Wv, wqkvT);
  k_qkv_tr<<<9280, 256, 0, stream>>>(xb, wqkvT, qbuf, kbuf, vbuf,
                                     W1, W2, Wout, w1T, w2T, woutT);
  k_attn<<<512, 256, 0, stream>>>(qbuf, kbuf, vbuf, attx);
  k_gemm128p<<<dim3(8, 32), 256, 0, stream>>>(attx, w1T, b1, h1, 4096, 1024,
                                              1024);
  k_gemm128p<<<dim3(8, 32), 256, 0, stream>>>(h1, w2T, b2, h2, 4096, 1024,
                                              1024);
  k_gemm256<<<dim3(125, 16), 512, 0, stream>>>(h2, woutT, bout, out, 4096,
                                               32000, 1024);
}

// Round 13
// 449.108 us; speedup vs baseline: 1.0476x; 1.0476x over previous
//
#include <hip/hip_runtime.h>
#include <cstdint>
#include <cstddef>

// Problem constants: V=32000 D=1024 T=1024 H=16 HD=64 B=4
// ws layout (bytes):
//   xb     @ 0          8,388,608   x bf16 [4096][1024]  (reused as h2)
//   wqkvT  @ 8388608    6,291,456   [3072][1024] bf16
//   w1T    @ 14680064   2,097,152
//   w2T    @ 16777216   2,097,152
//   woutT  @ 18874368   65,536,000  [32000][1024] bf16
//   qbuf   @ 84410368   8,388,608   [B,H,T,64] bf16
//   kbuf   @ 92798976   8,388,608
//   vbuf   @ 101187584  8,388,608
//   attx   @ 109576192  8,388,608
//   h1     @ 117964800  8,388,608

#define DEV __device__ __forceinline__

typedef __attribute__((ext_vector_type(8))) short bf16x8;
typedef __attribute__((ext_vector_type(4))) float f32x4;

DEV unsigned short f2bf(float f) {
  unsigned u = __float_as_uint(f);
  u = (u + 0x7fffu + ((u >> 16) & 1u)) >> 16;
  return (unsigned short)u;
}

DEV void stage16(const void* g, void* l) {   // async global->LDS, 16B/lane
  __builtin_amdgcn_global_load_lds(
      (const __attribute__((address_space(1))) unsigned int*)g,
      (__attribute__((address_space(3))) unsigned int*)l, 16, 0, 0);
}

// ---------------- prep: embed (blocks 0..4095) + pack_qkv (4096..4863) ------
__global__ __launch_bounds__(256) void k_prep(
    const int* __restrict__ idx, const float* __restrict__ tok,
    const float* __restrict__ pos, unsigned short* __restrict__ xb,
    const float* __restrict__ Wq, const float* __restrict__ Wk,
    const float* __restrict__ Wv, unsigned short* __restrict__ wqkvT) {
  __shared__ float tile[64][65];
  int b = blockIdx.x;
  int tid = threadIdx.x;
  if (b < 4096) {
    int i = b * 256 + tid;
    int row = i >> 8;
    int c4 = i & 255;
    int t = row & 1023;
    int tokid = idx[row];
    const float4 a = ((const float4*)tok)[(size_t)tokid * 256 + c4];
    const float4 p = ((const float4*)pos)[(size_t)t * 256 + c4];
    ushort4 o;
    o.x = f2bf(a.x + p.x); o.y = f2bf(a.y + p.y);
    o.z = f2bf(a.z + p.z); o.w = f2bf(a.w + p.w);
    ((ushort4*)xb)[i] = o;
    return;
  }
  int blk = b - 4096;
  int p = blk >> 8, h = (blk >> 4) & 15, d0 = (blk & 15) * 64;
  const float* W = (p == 0) ? Wq : ((p == 1) ? Wk : Wv);
  int rq = tid >> 6, cc = tid & 63;
#pragma unroll
  for (int it = 0; it < 16; ++it) {
    int dr = it * 4 + rq;
    tile[dr][cc] = W[((size_t)h * 1024 + d0 + dr) * 64 + cc];
  }
  __syncthreads();
#pragma unroll
  for (int it = 0; it < 16; ++it) {
    int e = it * 4 + rq;
    wqkvT[((size_t)(p * 1024 + h * 64 + e)) * 1024 + d0 + cc] = f2bf(tile[cc][e]);
  }
}

// -------- merged transpose+cast: W1, W2, Wout in ONE launch -----------------
__global__ __launch_bounds__(256) void k_transpose_all(
    const float* __restrict__ W1, const float* __restrict__ W2,
    const float* __restrict__ Wout, unsigned short* __restrict__ w1T,
    unsigned short* __restrict__ w2T, unsigned short* __restrict__ woutT) {
  __shared__ float tile[64][65];
  int b = blockIdx.x;
  const float* in;
  unsigned short* outp;
  int C, bx, by;
  if (b < 256)      { in = W1;   outp = w1T;   C = 1024;  bx = b & 15; by = b >> 4; }
  else if (b < 512) { b -= 256; in = W2;  outp = w2T;  C = 1024;  bx = b & 15; by = b >> 4; }
  else              { b -= 512; in = Wout; outp = woutT; C = 32000; bx = b % 500; by = b / 500; }
  const int R = 1024;
  const int c0 = bx * 64, r0 = by * 64;
  int tid = threadIdx.x, rq = tid >> 6, cc = tid & 63;
#pragma unroll
  for (int it = 0; it < 16; ++it) {
    int r = it * 4 + rq;
    tile[r][cc] = in[(size_t)(r0 + r) * C + c0 + cc];
  }
  __syncthreads();
#pragma unroll
  for (int it = 0; it < 16; ++it) {
    int c = it * 4 + rq;
    outp[(size_t)(c0 + c) * R + r0 + cc] = f2bf(tile[cc][c]);
  }
}

// ------- pipelined 128x128 GEMM (QKV / FFN): r9 structure, 2 blocks/CU ------
// EP: 1 = bias+relu -> bf16; 3 = qkv split -> [B,H,T,64] bf16 (N=3072)
template <int EP>
__global__ __launch_bounds__(256, 2) void k_gemm128p(
    const unsigned short* __restrict__ A, const unsigned short* __restrict__ Bt,
    const float* __restrict__ bias, void* __restrict__ out0,
    void* __restrict__ out1, void* __restrict__ out2, int M, int N, int K) {
  __shared__ __align__(16) unsigned short sm[4 * 8192];  // shorts; 64 KB
  const int tid = threadIdx.x;
  const int lane = tid & 63, w = tid >> 6;
  const int wr = w >> 1, wc = w & 1;
  const int fr = lane & 15, fg = lane >> 4;
  const int pch = (fg ^ ((fr >> 1) & 3)) << 3;

  const int nwg = gridDim.x * gridDim.y;
  int wg = blockIdx.y * gridDim.x + blockIdx.x;
  if ((nwg & 7) == 0) wg = (wg & 7) * (nwg >> 3) + (wg >> 3);
  const int m0 = (wg % gridDim.y) * 128;
  const int n0 = (wg / gridDim.y) * 128;

  const int srow = tid >> 2;
  const int sch = (((tid & 3) ^ ((srow >> 1) & 3))) * 8;
  const unsigned short* Ab0 = A + (size_t)(m0 + srow) * K + sch;
  const unsigned short* Ab1 = A + (size_t)(m0 + 64 + srow) * K + sch;
  const unsigned short* Bb0 = Bt + (size_t)(n0 + srow) * K + sch;
  const unsigned short* Bb1 = Bt + (size_t)(n0 + 64 + srow) * K + sch;
  const int NT = K >> 5;

#define STAGE_T(t, bb)                                                      \
  do {                                                                      \
    stage16(Ab0 + (t) * 32, &sm[(bb) * 8192 + tid * 8]);                    \
    stage16(Ab1 + (t) * 32, &sm[(bb) * 8192 + 2048 + tid * 8]);             \
    stage16(Bb0 + (t) * 32, &sm[(bb) * 8192 + 4096 + tid * 8]);             \
    stage16(Bb1 + (t) * 32, &sm[(bb) * 8192 + 6144 + tid * 8]);             \
  } while (0)

#define RD_ALL(dA, dB, bb)                                                  \
  do {                                                                      \
    const unsigned short* b_ = &sm[(bb) * 8192];                            \
    _Pragma("unroll") for (int m_ = 0; m_ < 4; ++m_)                        \
      dA[m_] = *(const bf16x8*)&b_[(wr * 64 + m_ * 16 + fr) * 32 + pch];    \
    _Pragma("unroll") for (int n_ = 0; n_ < 4; ++n_)                        \
      dB[n_] = *(const bf16x8*)&b_[4096 + (wc * 64 + n_ * 16 + fr) * 32 + pch]; \
  } while (0)

#define MFMA16(a, b)                                                        \
  do {                                                                      \
    __builtin_amdgcn_s_setprio(1);                                          \
    _Pragma("unroll") for (int m_ = 0; m_ < 4; ++m_)                        \
    _Pragma("unroll") for (int n_ = 0; n_ < 4; ++n_)                        \
      acc[m_][n_] = __builtin_amdgcn_mfma_f32_16x16x32_bf16(                \
          a[m_], b[n_], acc[m_][n_], 0, 0, 0);                              \
    __builtin_amdgcn_s_setprio(0);                                          \
  } while (0)

#define TB128(t, cA, cB, nA, nB)                                            \
  do {                                                                      \
    if ((t) + 3 < NT) STAGE_T((t) + 3, ((t) + 3) & 3);                      \
    if ((t) + 1 < NT) RD_ALL(nA, nB, ((t) + 1) & 3);                        \
    MFMA16(cA, cB);                                                         \
    if ((t) + 3 < NT) {                                                     \
      asm volatile("s_waitcnt vmcnt(4)" ::: "memory");                      \
    } else {                                                                \
      asm volatile("s_waitcnt vmcnt(0)" ::: "memory");                      \
    }                                                                       \
    __builtin_amdgcn_s_barrier();                                           \
  } while (0)

  f32x4 zero = {0.f, 0.f, 0.f, 0.f};
  f32x4 acc[4][4];
#pragma unroll
  for (int m = 0; m < 4; ++m)
#pragma unroll
    for (int n = 0; n < 4; ++n) acc[m][n] = zero;

  STAGE_T(0, 0); STAGE_T(1, 1); STAGE_T(2, 2);
  asm volatile("s_waitcnt vmcnt(4)" ::: "memory");   // tiles 0,1 resident
  __builtin_amdgcn_s_barrier();

  bf16x8 xA[4], xB[4], yA[4], yB[4];
  RD_ALL(xA, xB, 0);
  for (int t = 0; t < NT; t += 2) {
    TB128(t, xA, xB, yA, yB);
    TB128(t + 1, yA, yB, xA, xB);
  }
#undef STAGE_T
#undef RD_ALL
#undef MFMA16
#undef TB128

#pragma unroll
  for (int m = 0; m < 4; ++m) {
#pragma unroll
    for (int n = 0; n < 4; ++n) {
      const int rb = m0 + wr * 64 + m * 16 + fg * 4;
      const int cc = n0 + wc * 64 + n * 16 + fr;
#pragma unroll
      for (int i = 0; i < 4; ++i) {
        float v = acc[m][n][i];
        const int r = rb + i;
        if (EP == 1) {
          v += bias[cc];
          v = v > 0.f ? v : 0.f;
          ((unsigned short*)out0)[(size_t)r * N + cc] = f2bf(v);
        } else if (EP == 3) {
          int p = cc >> 10, rem = cc & 1023;
          int h = rem >> 6, e = rem & 63;
          int b = r >> 10, t2 = r & 1023;
          unsigned short* dst =
              (p == 0) ? (unsigned short*)out0
                       : ((p == 1) ? (unsigned short*)out1 : (unsigned short*)out2);
          dst[(((size_t)(b * 16 + h) * 1024) + t2) * 64 + e] = f2bf(v);
        }
      }
    }
  }
}

// ---------- 256x256 logits GEMM: r9 loop + A-resident XCD swizzle -----------
// NEW swizzle: each XCD owns 2 M-block rows (A-panels 1MB -> L2-resident for
// the whole kernel) and sweeps N-panels, alternating its two m-rows so each
// B-panel is read twice back-to-back (2nd = L2 hit). XCDs advance through n
// in rough lockstep -> each B-panel HBM-fetched ~once, L3-served otherwise.
// (r12 analysis: old N-resident swizzle re-swept the 8MB A per N-panel ->
//  FETCH 322MB vs 74MB ideal.)
__global__ __launch_bounds__(512, 2) void k_gemm256(
    const unsigned short* __restrict__ A, const unsigned short* __restrict__ Bt,
    const float* __restrict__ bias, float* __restrict__ out,
    int M, int N, int K) {
  __shared__ __align__(16) unsigned short sm[4 * 16384];   // 128 KB
  const int tid = threadIdx.x;
  const int lane = tid & 63, wid = tid >> 6;
  const int wr = wid >> 2, wc = wid & 3;          // 2 x 4 wave grid
  const int fr = lane & 15, fg = lane >> 4;
  const int pch = (fg ^ ((fr >> 1) & 3)) << 3;    // swizzled read chunk

  // grid (125,16) -> nwg 2000. xcd = wg&7, j = wg>>3 in [0,250):
  //   m-block = xcd*2 + (j&1)  (16 values), n-panel = j>>1  (125 values)
  const int wg0 = blockIdx.y * gridDim.x + blockIdx.x;
  const int xcd = wg0 & 7, j = wg0 >> 3;
  const int m0 = (xcd * 2 + (j & 1)) * 256;
  const int n0 = (j >> 1) * 256;

  const int srow = tid >> 2;
  const int scol = (((tid & 3) ^ ((srow >> 1) & 3))) * 8;  // pre-swizzled
  const int NT = K >> 5;                                   // 32 K-tiles of 32

#define STAGE_A(t, bb)                                                      \
  do {                                                                      \
    const unsigned short* g = A + (size_t)(m0 + srow) * K + (t) * 32 + scol; \
    stage16(g, &sm[(bb) * 16384 + tid * 8]);                                \
    stage16(g + (size_t)128 * K, &sm[(bb) * 16384 + 4096 + tid * 8]);       \
  } while (0)
#define STAGE_B(t, bb)                                                      \
  do {                                                                      \
    const unsigned short* g = Bt + (size_t)(n0 + srow) * K + (t) * 32 + scol; \
    stage16(g, &sm[(bb) * 16384 + 8192 + tid * 8]);                         \
    stage16(g + (size_t)128 * K, &sm[(bb) * 16384 + 8192 + 4096 + tid * 8]); \
  } while (0)

#define RD_G0(dA, dB, base)                                                 \
  do {                                                                      \
    _Pragma("unroll") for (int m_ = 0; m_ < 4; ++m_)                        \
      dA[m_] = *(const bf16x8*)&(base)[(wr * 128 + m_ * 16 + fr) * 32 + pch]; \
    _Pragma("unroll") for (int n_ = 0; n_ < 4; ++n_)                        \
      dB[n_] = *(const bf16x8*)&(base)[8192 + (wc * 64 + n_ * 16 + fr) * 32 + pch]; \
  } while (0)
#define RD_AHI(dA, base)                                                    \
  do {                                                                      \
    _Pragma("unroll") for (int m_ = 0; m_ < 4; ++m_)                        \
      dA[m_] = *(const bf16x8*)&(base)[(wr * 128 + (m_ + 4) * 16 + fr) * 32 + pch]; \
  } while (0)

#define MFMA_G(rbase, a, b)                                                 \
  do {                                                                      \
    __builtin_amdgcn_s_setprio(1);                                          \
    _Pragma("unroll") for (int m_ = 0; m_ < 4; ++m_)                        \
    _Pragma("unroll") for (int n_ = 0; n_ < 4; ++n_)                        \
      acc[(rbase) + m_][n_] = __builtin_amdgcn_mfma_f32_16x16x32_bf16(      \
          a[m_], b[n_], acc[(rbase) + m_][n_], 0, 0, 0);                    \
    __builtin_amdgcn_s_setprio(0);                                          \
  } while (0)

#define TILE_BODY(t, curA, curB, nxtA, nxtB)                                \
  do {                                                                      \
    const unsigned short* Ab_ = &sm[((t) & 3) * 16384];                     \
    bf16x8 a1_[4];                                                          \
    RD_AHI(a1_, Ab_);                                                       \
    if ((t) + 3 < NT) STAGE_A((t) + 3, ((t) + 3) & 3);                      \
    MFMA_G(0, curA, curB);                                                  \
    if ((t) + 1 < NT) {                                                     \
      const unsigned short* An_ = &sm[(((t) + 1) & 3) * 16384];             \
      RD_G0(nxtA, nxtB, An_);                                               \
    }                                                                       \
    if ((t) + 3 < NT) STAGE_B((t) + 3, ((t) + 3) & 3);                      \
    MFMA_G(4, a1_, curB);                                                   \
    if ((t) + 3 < NT) {                                                     \
      asm volatile("s_waitcnt vmcnt(4)" ::: "memory");                      \
    } else {                                                                \
      asm volatile("s_waitcnt vmcnt(0)" ::: "memory");                      \
    }                                                                       \
    __builtin_amdgcn_s_barrier();                                           \
  } while (0)

  f32x4 zero = {0.f, 0.f, 0.f, 0.f};
  f32x4 acc[8][4];
#pragma unroll
  for (int m = 0; m < 8; ++m)
#pragma unroll
    for (int n = 0; n < 4; ++n) acc[m][n] = zero;

  STAGE_A(0, 0); STAGE_B(0, 0);
  STAGE_A(1, 1); STAGE_B(1, 1);
  STAGE_A(2, 2); STAGE_B(2, 2);
  asm volatile("s_waitcnt vmcnt(4)" ::: "memory");
  __builtin_amdgcn_s_barrier();

  bf16x8 xA[4], xB[4], yA[4], yB[4];
  RD_G0(xA, xB, &sm[0]);          // tile 0 group-0 regs

  for (int t = 0; t < NT; t += 2) {
    TILE_BODY(t, xA, xB, yA, yB);
    TILE_BODY(t + 1, yA, yB, xA, xB);
  }
#undef STAGE_A
#undef STAGE_B
#undef RD_G0
#undef RD_AHI
#undef MFMA_G
#undef TILE_BODY

  // ---- epilogue: LDS slab transpose -> coalesced f32x4 NT stores ----
  float* lds = (float*)sm;        // [32][260] f32, padded
  float bsv[4];
#pragma unroll
  for (int n = 0; n < 4; ++n) bsv[n] = bias[n0 + wc * 64 + n * 16 + fr];

  for (int m = 0; m < 8; ++m) {
#pragma unroll
    for (int n = 0; n < 4; ++n) {
      const int c = wc * 64 + n * 16 + fr;
#pragma unroll
      for (int i = 0; i < 4; ++i)
        lds[(wr * 16 + fg * 4 + i) * 260 + c] = acc[m][n][i] + bsv[n];
    }
    __syncthreads();
#pragma unroll
    for (int p = 0; p < 4; ++p) {
      const int rr = p * 8 + (tid >> 6);
      const int c4 = (tid & 63) * 4;
      f32x4 v = *(const f32x4*)&lds[rr * 260 + c4];
      const int grow = m0 + ((rr < 16) ? (m * 16 + rr) : (128 + m * 16 + rr - 16));
      __builtin_nontemporal_store(v, (f32x4*)&out[(size_t)grow * N + n0 + c4]);
    }
    __syncthreads();
  }
}

// ---------------- fused causal flash attention, Q-tile 128 ------------------
__global__ __launch_bounds__(256) void k_attn(
    const unsigned short* __restrict__ qb, const unsigned short* __restrict__ kb,
    const unsigned short* __restrict__ vb, unsigned short* __restrict__ attx) {
  __shared__ __align__(16) unsigned short Klds[64][72];
  __shared__ __align__(16) unsigned short Vt[64][72];
  __shared__ __align__(16) unsigned short Plds[2][4][16][72];
  const int wg = blockIdx.x;
  const int xcd = wg & 7, idxr = wg >> 3;
  const int bh = xcd * 8 + (idxr >> 3);     // 8 bh per XCD
  const int qt = 7 - (idxr & 7);            // heavy-first within XCD
  const int tid = threadIdx.x;
  const int w = tid >> 6, lane = tid & 63;
  const int fr = lane & 15, g = lane >> 4;
  const size_t base = (size_t)bh * (1024 * 64);
  const int qbase = qt * 128;

  bf16x8 qf[2][2];
#pragma unroll
  for (int qs = 0; qs < 2; ++qs)
#pragma unroll
    for (int t = 0; t < 2; ++t)
      qf[qs][t] = *(const bf16x8*)&qb[base +
          (size_t)(qbase + qs * 64 + w * 16 + fr) * 64 + t * 32 + g * 8];

  f32x4 zero = {0.f, 0.f, 0.f, 0.f};
  f32x4 o[2][4];
#pragma unroll
  for (int qs = 0; qs < 2; ++qs)
#pragma unroll
    for (int hb = 0; hb < 4; ++hb) o[qs][hb] = zero;
  float m_s[2] = {-3.0e38f, -3.0e38f}, l_s[2] = {0.f, 0.f};

  const int NTKV = 2 * qt + 2;
  for (int jt = 0; jt < NTKV; ++jt) {
    const int kvb = jt * 64;
#pragma unroll
    for (int it = 0; it < 2; ++it) {       // stage K rows + V transposed
      int c = tid + it * 256;
      int r = c >> 3, e0 = (c & 7) * 8;
      uint4 kd = *(const uint4*)&kb[base + (size_t)(kvb + r) * 64 + e0];
      *(uint4*)&Klds[r][e0] = kd;
      uint4 vd = *(const uint4*)&vb[base + (size_t)(kvb + r) * 64 + e0];
      const unsigned short* vs = (const unsigned short*)&vd;
#pragma unroll
      for (int j = 0; j < 8; ++j) Vt[e0 + j][r] = vs[j];
    }
    __syncthreads();

#pragma unroll
    for (int qs = 0; qs < 2; ++qs) {
      const int qlo = qbase + qs * 64;
      if (kvb > qlo + 63) continue;        // fully-masked subtile (uniform)
      const int q_abs = qlo + w * 16 + fr;

      f32x4 st[4];
#pragma unroll
      for (int f = 0; f < 4; ++f) {
        st[f] = zero;
#pragma unroll
        for (int t = 0; t < 2; ++t) {
          bf16x8 kf = *(const bf16x8*)&Klds[f * 16 + fr][t * 32 + g * 8];
          st[f] = __builtin_amdgcn_mfma_f32_16x16x32_bf16(kf, qf[qs][t], st[f],
                                                          0, 0, 0);
        }
      }
      float sv[4][4];
      float tm = -3.0e38f;
#pragma unroll
      for (int f = 0; f < 4; ++f)
#pragma unroll
        for (int i = 0; i < 4; ++i) {
          int kv = kvb + f * 16 + g * 4 + i;
          float s = st[f][i] * 0.125f;
          if (kv > q_abs) s = -3.0e38f;
          sv[f][i] = s;
          tm = fmaxf(tm, s);
        }
      tm = fmaxf(tm, __shfl_xor(tm, 16));
      tm = fmaxf(tm, __shfl_xor(tm, 32));
      float mnew = fmaxf(m_s[qs], tm);
      float scale = expf(m_s[qs] - mnew);
      float lsum = 0.f;
#pragma unroll
      for (int f = 0; f < 4; ++f)
#pragma unroll
        for (int i = 0; i < 4; ++i) {
          float pv = expf(sv[f][i] - mnew);
          lsum += pv;
          Plds[qs][w][fr][f * 16 + g * 4 + i] = f2bf(pv);
        }
      lsum += __shfl_xor(lsum, 16);
      lsum += __shfl_xor(lsum, 32);
      l_s[qs] = l_s[qs] * scale + lsum;
      m_s[qs] = mnew;
#pragma unroll
      for (int i = 0; i < 4; ++i) {
        float sc = __shfl(scale, g * 4 + i);
#pragma unroll
        for (int hb = 0; hb < 4; ++hb) o[qs][hb][i] *= sc;
      }
      asm volatile("s_waitcnt lgkmcnt(0)" ::: "memory");
      __builtin_amdgcn_sched_barrier(0);
#pragma unroll
      for (int t = 0; t < 2; ++t) {
        bf16x8 pf = *(const bf16x8*)&Plds[qs][w][fr][t * 32 + g * 8];
#pragma unroll
        for (int hb = 0; hb < 4; ++hb) {
          bf16x8 vf = *(const bf16x8*)&Vt[hb * 16 + fr][t * 32 + g * 8];
          o[qs][hb] = __builtin_amdgcn_mfma_f32_16x16x32_bf16(pf, vf, o[qs][hb],
                                                              0, 0, 0);
        }
      }
    }
    __syncthreads();                       // all waves done with K/Vt
  }

  const int b = bh >> 4, h = bh & 15;
#pragma unroll
  for (int qs = 0; qs < 2; ++qs) {
    const float inv = 1.f / l_s[qs];
#pragma unroll
    for (int i = 0; i < 4; ++i) {
      float sc = __shfl(inv, g * 4 + i);
      int trow = qbase + qs * 64 + w * 16 + g * 4 + i;
      size_t rowoff = ((size_t)(b * 1024 + trow)) * 1024 + h * 64;
#pragma unroll
      for (int hb = 0; hb < 4; ++hb)
        attx[rowoff + hb * 16 + fr] = f2bf(o[qs][hb][i] * sc);
    }
  }
}

// ------------------------------- launch -------------------------------------
extern "C" void kernel_launch(void* const* d_in, const int* in_sizes, int n_in,
                              void* d_out, int out_size, void* d_ws,
                              size_t ws_size, hipStream_t stream) {
  const int* idx = (const int*)d_in[0];
  const float* tok = (const float*)d_in[1];
  const float* pos = (const float*)d_in[2];
  const float* Wq = (const float*)d_in[3];
  const float* Wk = (const float*)d_in[4];
  const float* Wv = (const float*)d_in[5];
  const float* W1 = (const float*)d_in[6];
  const float* b1 = (const float*)d_in[7];
  const float* W2 = (const float*)d_in[8];
  const float* b2 = (const float*)d_in[9];
  const float* Wout = (const float*)d_in[10];
  const float* bout = (const float*)d_in[11];
  float* out = (float*)d_out;

  char* ws = (char*)d_ws;
  unsigned short* xb    = (unsigned short*)(ws + 0);
  unsigned short* wqkvT = (unsigned short*)(ws + 8388608);
  unsigned short* w1T   = (unsigned short*)(ws + 14680064);
  unsigned short* w2T   = (unsigned short*)(ws + 16777216);
  unsigned short* woutT = (unsigned short*)(ws + 18874368);
  unsigned short* qbuf  = (unsigned short*)(ws + 84410368);
  unsigned short* kbuf  = (unsigned short*)(ws + 92798976);
  unsigned short* vbuf  = (unsigned short*)(ws + 101187584);
  unsigned short* attx  = (unsigned short*)(ws + 109576192);
  unsigned short* h1    = (unsigned short*)(ws + 117964800);
  unsigned short* h2    = xb;

  k_prep<<<4864, 256, 0, stream>>>(idx, tok, pos, xb, Wq, Wk, Wv, wqkvT);
  k_transpose_all<<<8512, 256, 0, stream>>>(W1, W2, Wout, w1T, w2T, woutT);

  k_gemm128p<3><<<dim3(24, 32), 256, 0, stream>>>(xb, wqkvT, nullptr, qbuf,
                                                  kbuf, vbuf, 4096, 3072, 1024);
  k_attn<<<512, 256, 0, stream>>>(qbuf, kbuf, vbuf, attx);
  k_gemm128p<1><<<dim3(8, 32), 256, 0, stream>>>(attx, w1T, b1, h1, nullptr,
                                                 nullptr, 4096, 1024, 1024);
  k_gemm128p<1><<<dim3(8, 32), 256, 0, stream>>>(h1, w2T, b2, h2, nullptr,
                                                 nullptr, 4096, 1024, 1024);
  k_gemm256<<<dim3(125, 16), 512, 0, stream>>>(h2, woutT, bout, out, 4096,
                                               32000, 1024);
}